// Round 8
// baseline (197.226 us; speedup 1.0000x reference)
//
#include <hip/hip_runtime.h>
#include <cmath>

#define NBLK 3456   // 2 * 12 * 12 * 12 blocks of 16^3

#define DPP_SHR1 0x111   // y-1 neighbor source (row_shr:1)
#define DPP_SHL1 0x101   // y+1 neighbor source (row_shl:1)

template<int CTRL>
__device__ __forceinline__ float dpp_keep_f(float v) {
  return __int_as_float(__builtin_amdgcn_update_dpp(
      __float_as_int(v), __float_as_int(v), CTRL, 0xF, 0xF, false));
}
template<int CTRL>
__device__ __forceinline__ float dpp_zero_f(float v) {
  return __int_as_float(__builtin_amdgcn_update_dpp(
      0, __float_as_int(v), CTRL, 0xF, 0xF, true));
}
template<int CTRL>
__device__ __forceinline__ unsigned dpp_keep_u(unsigned v) {
  return (unsigned)__builtin_amdgcn_update_dpp((int)v, (int)v, CTRL, 0xF, 0xF, false);
}
template<int CTRL>
__device__ __forceinline__ unsigned dpp_zero_u(unsigned v) {
  return (unsigned)__builtin_amdgcn_update_dpp(0, (int)v, CTRL, 0xF, 0xF, true);
}

// LDS column layout: float4 chunk cg (z=4cg..4cg+3) of column (x,y) at
// index (cg*18 + x+1)*16 + y.  x pad slots at x=-1 -> 0 and x=16 -> 17.
#define COL_IDX(cg, xx) (((cg)*18 + (xx) + 1)*16 + y)

// 512 threads, 8 z per thread (zh = which z-half). Register arrays halved to
// cross the 64-VGPR occupancy cliff (R6: 76 VGPR -> stuck at 4 waves/SIMD).
// z-half boundary exchange = one shfl_xor(16) (partner lane within wave).
// Double LDS buffers (bufE/bufT) cut barriers to 2 per stencil iteration.
// LDS total 39,168 B -> 4 blocks x 8 waves = 32 waves/CU if VGPR <= 64.
__global__ __launch_bounds__(512)
void fused_blocks(const float* __restrict__ pred, const float* __restrict__ gtp,
                  float* __restrict__ ws)
{
  __shared__ float4   bufE[1152];   // erode chain (+INF pads)
  __shared__ float4   bufT[1152];   // laplacian sums (0) then dilate (-INF)
  __shared__ unsigned mA[288];      // gt exchange A
  __shared__ unsigned mB[288];      // gt exchange B (reused as reduction buf)
  float* red = (float*)mB;          // 72 floats

  const int tid = threadIdx.x;
  const int y  = tid & 15;
  const int zh = (tid >> 4) & 1;
  const int x  = tid >> 5;

  const int b  = blockIdx.x;
  const int n  = b / 1728;
  const int r  = b - n * 1728;
  const int bz = r / 144;
  const int r2 = r - bz * 144;
  const int bx = r2 / 12;
  const int by = r2 - bx * 12;

  const size_t base = (size_t)(n * 192 + bz * 16 + zh * 8) * 36864
                    + (size_t)(bx * 16 + x) * 192 + (size_t)(by * 16 + y);

  const float INF = __builtin_inff();
  const int cg0 = zh * 2, cg1 = zh * 2 + 1;

  auto write_padsE = [&](float pv) {
    if (tid < 128) {
      const int cg = tid >> 5;
      const int xi = ((tid >> 4) & 1) ? 17 : 0;
      bufE[(cg * 18 + xi) * 16 + (tid & 15)] = make_float4(pv, pv, pv, pv);
    }
  };
  auto write_padsT = [&](float pv) {
    if (tid >= 128 && tid < 256) {
      const int t = tid - 128;
      const int cg = t >> 5;
      const int xi = ((t >> 4) & 1) ? 17 : 0;
      bufT[(cg * 18 + xi) * 16 + (t & 15)] = make_float4(pv, pv, pv, pv);
    }
  };

  // ---- loads: p half-column + g half-column ----
  float p[8];
  #pragma unroll
  for (int j = 0; j < 8; ++j) p[j] = pred[base + (size_t)j * 36864];

  unsigned own8 = 0u;
  float sp2 = 0.f, spg = 0.f;
  #pragma unroll
  for (int j = 0; j < 8; ++j) {
    float gz = gtp[base + (size_t)j * 36864];
    sp2 = fmaf(p[j], p[j], sp2);
    spg = fmaf(p[j], gz, spg);
    if (gz > 0.5f) own8 |= (1u << j);
  }
  unsigned gsh = own8 << (zh * 8);
  unsigned gmfull = gsh | (unsigned)__shfl_xor((int)gsh, 16);  // 16-bit column

  // ---------------- pred boundary (3^3 laplacian, zero pad) ----------------
  float szy[8];
  {
    float sy[8];
    #pragma unroll
    for (int j = 0; j < 8; ++j) {
      float v = p[j];
      sy[j] = v + dpp_zero_f<DPP_SHR1>(v) + dpp_zero_f<DPP_SHL1>(v);
    }
    float bsy = __shfl_xor(zh ? sy[0] : sy[7], 16);
    #pragma unroll
    for (int j = 0; j < 8; ++j) {
      float prev = (j > 0) ? sy[j-1] : (zh ? bsy : 0.f);
      float next = (j < 7) ? sy[j+1] : (zh ? 0.f : bsy);
      szy[j] = prev + sy[j] + next;
    }
  }
  bufT[COL_IDX(cg0, x)] = make_float4(szy[0], szy[1], szy[2], szy[3]);
  bufT[COL_IDX(cg1, x)] = make_float4(szy[4], szy[5], szy[6], szy[7]);
  write_padsT(0.f);
  bufE[COL_IDX(cg0, x)] = make_float4(p[0], p[1], p[2], p[3]);
  bufE[COL_IDX(cg1, x)] = make_float4(p[4], p[5], p[6], p[7]);
  write_padsE(INF);
  __syncthreads();                                             // P1

  unsigned pm8 = 0u;
  #pragma unroll
  for (int c = 0; c < 2; ++c) {
    float4 a4 = bufT[COL_IDX(cg0 + c, x - 1)];
    float4 b4 = bufT[COL_IDX(cg0 + c, x + 1)];
    #pragma unroll
    for (int jj = 0; jj < 4; ++jj) {
      const int j = 4*c + jj;
      float bb = fmaf(27.f, p[j], -(szy[j] + ((&a4.x)[jj] + (&b4.x)[jj])));
      if (bb > 0.1f) pm8 |= (1u << j);
    }
  }

  // ---------------- pred soft skeleton (4x erode+dilate) ----------------
  float cur[8], skl[8];
  #pragma unroll
  for (int j = 0; j < 8; ++j) { cur[j] = p[j]; skl[j] = 0.f; }

  for (int k = 0; k < 4; ++k) {
    // erode: min over 7-point cross
    float en[8];
    float bcur = __shfl_xor(zh ? cur[0] : cur[7], 16);
    #pragma unroll
    for (int c = 0; c < 2; ++c) {
      float4 a4 = bufE[COL_IDX(cg0 + c, x - 1)];
      float4 b4 = bufE[COL_IDX(cg0 + c, x + 1)];
      #pragma unroll
      for (int jj = 0; jj < 4; ++jj) {
        const int j = 4*c + jj;
        float v  = cur[j];
        float m1 = fminf(dpp_keep_f<DPP_SHR1>(v), v);
        float m2 = fminf(dpp_keep_f<DPP_SHL1>(v), m1);
        float zl = (j > 0) ? cur[j-1] : (zh ? bcur : v);
        float zu = (j < 7) ? cur[j+1] : (zh ? v : bcur);
        en[j] = fminf(fminf(m2, fminf(zl, zu)),
                      fminf((&a4.x)[jj], (&b4.x)[jj]));
      }
    }
    __syncthreads();                     // A: bufE reads + prev bufT reads done

    bufE[COL_IDX(cg0, x)] = make_float4(en[0], en[1], en[2], en[3]);
    bufE[COL_IDX(cg1, x)] = make_float4(en[4], en[5], en[6], en[7]);
    write_padsE(INF);
    // dilate(en) in y,z
    float ty[8];
    #pragma unroll
    for (int j = 0; j < 8; ++j) {
      float v = en[j];
      ty[j] = fmaxf(fmaxf(dpp_keep_f<DPP_SHR1>(v), dpp_keep_f<DPP_SHL1>(v)), v);
    }
    float bty = __shfl_xor(zh ? ty[0] : ty[7], 16);
    #pragma unroll
    for (int c = 0; c < 2; ++c) {
      float4 w;
      #pragma unroll
      for (int jj = 0; jj < 4; ++jj) {
        const int j = 4*c + jj;
        float prev = (j > 0) ? ty[j-1] : (zh ? bty : -INF);
        float next = (j < 7) ? ty[j+1] : (zh ? -INF : bty);
        (&w.x)[jj] = fmaxf(fmaxf(prev, ty[j]), next);
      }
      bufT[COL_IDX(cg0 + c, x)] = w;
    }
    write_padsT(-INF);
    __syncthreads();                     // B: tz visible

    #pragma unroll
    for (int c = 0; c < 2; ++c) {
      float4 a4 = bufT[COL_IDX(cg0 + c, x - 1)];
      float4 b4 = bufT[COL_IDX(cg0 + c, x + 1)];
      float4 c4 = bufT[COL_IDX(cg0 + c, x)];
      #pragma unroll
      for (int jj = 0; jj < 4; ++jj) {
        const int j = 4*c + jj;
        float D = fmaxf(fmaxf((&a4.x)[jj], (&b4.x)[jj]), (&c4.x)[jj]);
        float delta = fmaxf(cur[j] - D, 0.f);
        skl[j] += fmaxf(fmaf(-skl[j], delta, delta), 0.f);
        cur[j] = en[j];
      }
    }
  }

  // ---------------- gt phase: exact bit-domain morphology ----------------
  // (full 16-bit column masks, duplicated across zh partners; z = bit shifts)
  unsigned ly  = gmfull & dpp_zero_u<DPP_SHR1>(gmfull) & dpp_zero_u<DPP_SHL1>(gmfull);
  unsigned lzy = ly & (ly >> 1) & ((ly << 1) & 0xFFFFu);
  if (!zh) mA[(x + 1) * 16 + y] = lzy;
  if (tid < 32) mA[((tid >> 4) ? 17 : 0) * 16 + (tid & 15)] = 0u;
  __syncthreads();                                             // G0
  unsigned gm_bdr = gmfull & ~(mA[x * 16 + y] & lzy & mA[(x + 2) * 16 + y]);

  unsigned curm = gmfull, sklm = 0u;
  for (int k = 0; k < 4; ++k) {
    if (!zh) mB[(x + 1) * 16 + y] = curm;
    if (tid < 32) mB[((tid >> 4) ? 17 : 0) * 16 + (tid & 15)] = 0xFFFFu;
    __syncthreads();                                           // G1
    unsigned em = curm
        & dpp_keep_u<DPP_SHR1>(curm) & dpp_keep_u<DPP_SHL1>(curm)
        & ((curm >> 1) | 0x8000u) & ((curm << 1) | 1u)
        & mB[x * 16 + y] & mB[(x + 2) * 16 + y];
    em &= 0xFFFFu;
    unsigned dy  = em | dpp_keep_u<DPP_SHR1>(em) | dpp_keep_u<DPP_SHL1>(em);
    unsigned dzy = (dy | (dy >> 1) | (dy << 1)) & 0xFFFFu;
    if (!zh) mA[(x + 1) * 16 + y] = dzy;
    if (tid < 32) mA[((tid >> 4) ? 17 : 0) * 16 + (tid & 15)] = 0u;
    __syncthreads();                                           // G2
    unsigned D = mA[x * 16 + y] | dzy | mA[(x + 2) * 16 + y];
    sklm |= curm & ~D;
    curm = em;
  }

  // ---------------- per-block reductions (own halves only) ----------------
  float vals[9];
  {
    unsigned sklm8  = (sklm   >> (zh * 8)) & 0xFFu;
    unsigned gmbdr8 = (gm_bdr >> (zh * 8)) & 0xFFu;
    float tcl = 0.f, scl = 0.f;
    #pragma unroll
    for (int j = 0; j < 8; ++j) {
      scl += skl[j];
      tcl += ((sklm8 >> j) & 1u) ? skl[j] : 0.f;
    }
    vals[0] = tcl;                                   // sum g_cl * p_cl
    vals[1] = scl;                                   // sum p_cl
    vals[2] = (float)__popc(sklm8);                  // sum g_cl
    vals[3] = (float)__popc(pm8 & gmbdr8);           // bdr tp
    vals[4] = (float)__popc(pm8);                    // sum p_bdr
    vals[5] = (float)__popc(gmbdr8);                 // sum g_bdr
    vals[6] = spg;                                   // dice: sum p*g
    vals[7] = sp2;                                   // dice: sum p*p
    vals[8] = (float)__popc(own8);                   // dice: sum g*g
  }
  #pragma unroll
  for (int j = 0; j < 9; ++j) {
    float v = vals[j];
    #pragma unroll
    for (int off = 32; off; off >>= 1) v += __shfl_xor(v, off);
    vals[j] = v;
  }
  if ((tid & 63) == 0) {       // red overlays mB: all mB reads done pre-G2(3)
    #pragma unroll
    for (int j = 0; j < 9; ++j) red[(tid >> 6) * 9 + j] = vals[j];
  }
  __syncthreads();                                             // R1
  if (tid == 0) {
    float t[9];
    #pragma unroll
    for (int j = 0; j < 9; ++j) {
      float s4 = 0.f;
      #pragma unroll
      for (int w = 0; w < 8; ++w) s4 += red[w * 9 + j];
      t[j] = s4;
    }
    const float s = 1e-8f;
    // boundary tversky
    float tp = t[3], fp = t[4] - t[3], fn = t[5] - t[3];
    float den = fp + fn + s;
    float alpha = 0.5f + 0.5f * ((fp + s) / den);
    float beta  = 0.5f + 0.5f * ((fn + s) / den);
    float lb = 1.f - (tp + s) / (tp + alpha * fp + beta * fn + s);
    // centerline tversky
    float tpc = t[0], fpc = t[1] - t[0], fnc = t[2] - t[0];
    float denc = fpc + fnc + s;
    float alphac = 0.5f + 0.5f * ((fpc + s) / denc);
    float betac  = 0.5f + 0.5f * ((fnc + s) / denc);
    float lc = 1.f - (tpc + s) / (tpc + alphac * fpc + betac * fnc + s);
    float* o = ws + (size_t)b * 8;
    o[0] = lb; o[1] = lc; o[2] = t[6]; o[3] = t[7]; o[4] = t[8];
  }
}

__global__ __launch_bounds__(256)
void finalize_kernel(const float* __restrict__ ws, const float* __restrict__ w1p,
                     const float* __restrict__ w2p, float* __restrict__ out)
{
  __shared__ double red2[20];
  double a[5] = {0.0, 0.0, 0.0, 0.0, 0.0};
  for (int i = threadIdx.x; i < NBLK; i += 256) {
    const float* o = ws + (size_t)i * 8;
    a[0] += (double)o[0];
    a[1] += (double)o[1];
    a[2] += (double)o[2];
    a[3] += (double)o[3];
    a[4] += (double)o[4];
  }
  #pragma unroll
  for (int j = 0; j < 5; ++j) {
    double v = a[j];
    #pragma unroll
    for (int off = 32; off; off >>= 1) v += __shfl_xor(v, off);
    if ((threadIdx.x & 63) == 0) red2[(threadIdx.x >> 6) * 5 + j] = v;
  }
  __syncthreads();
  if (threadIdx.x == 0) {
    double t[5];
    #pragma unroll
    for (int j = 0; j < 5; ++j) t[j] = red2[j] + red2[5 + j] + red2[10 + j] + red2[15 + j];
    double denom = t[3] + t[4];
    if (denom < 1e-6) denom = 1e-6;
    double dice = 2.0 * t[2] / denom;
    double dl = 1.0 - dice;
    double w1 = (double)w1p[0], w2 = (double)w2p[0];
    double edge = (t[0] / (w1 * w1) + t[1] / (w2 * w2)) / (2.0 * (double)NBLK)
                + log(1.0 + fabs(w1) * fabs(w2));
    out[0] = (float)((dice < 0.8) ? dl : (dl + edge));
  }
}

extern "C" void kernel_launch(void* const* d_in, const int* in_sizes, int n_in,
                              void* d_out, int out_size, void* d_ws, size_t ws_size,
                              hipStream_t stream)
{
  const float* pred = (const float*)d_in[0];
  const float* gtp  = (const float*)d_in[1];
  const float* w1   = (const float*)d_in[2];
  const float* w2   = (const float*)d_in[3];
  float* ws = (float*)d_ws;   // NBLK * 8 floats = 110,592 B

  fused_blocks<<<NBLK, 512, 0, stream>>>(pred, gtp, ws);
  finalize_kernel<<<1, 256, 0, stream>>>(ws, w1, w2, (float*)d_out);
}